// Round 3
// baseline (43.322 us; speedup 1.0000x reference)
//
#include <hip/hip_runtime.h>

typedef __attribute__((ext_vector_type(8))) short bf16x8;   // 8 bf16 bit-patterns (4 VGPRs)
typedef __attribute__((ext_vector_type(4))) float f32x4;

// fp32 -> bf16 round-to-nearest-even (bit trick; inputs are finite randoms)
__device__ __forceinline__ short f2bf(float x) {
    unsigned u = __builtin_bit_cast(unsigned, x);
    u += 0x7fffu + ((u >> 16) & 1u);
    return (short)(u >> 16);
}

// One wave per batch row. Features padded 27 -> 32 (2 MFMA row-tiles of 16).
// Gram = A*A^T via mfma_f32_16x16x32_bf16; the same fragment feeds both
// operand roles, so any per-lane k-permutation cancels — we load whatever
// chunk assignment gives full-line coverage per instruction.
//
// Output path: scatter the 351 triu values into a per-wave LDS row, then
// write to global with 6 CONTIGUOUS dword store instructions (256B fully
// covered per instruction). Scattered 4B global stores never present a full
// line per instruction -> L2 write-allocate fetches the line from HBM first
// (+23 MB hidden read traffic); contiguous stores are demonstrably
// allocate-free (the harness fills write 852 MB with FETCH_SIZE ~14 KB).
__global__ __launch_bounds__(256) void fi_mfma_kernel(
    const float* __restrict__ bottom,   // [B, 128]
    const float* __restrict__ emb,      // [B, 26, 128]
    float* __restrict__ out,            // [B, 351]
    int B)
{
    __shared__ float srow[4][352];               // per-wave staging row

    const int wave = threadIdx.x >> 6;
    const int lane = threadIdx.x & 63;
    const int r = blockIdx.x * 4 + wave;        // batch row
    if (r >= B) return;

    const int lrow = lane & 15;                 // feature-within-tile (frag row/col)
    const int g    = lane >> 4;                 // lane group 0..3

    // ---- load fp32 straight from global: 8 full-line instructions per tile ----
    f32x4 w[2][8];
    #pragma unroll
    for (int t = 0; t < 2; ++t) {
        const int f = 16 * t + lrow;
        const bool valid = (f < 27);
        const float* rowp = (f == 0)
            ? (bottom + (size_t)r * 128)
            : (emb + ((size_t)r * 26 + (valid ? (f - 1) : 0)) * 128);
        #pragma unroll
        for (int m = 0; m < 8; ++m) {
            if (valid) {
                w[t][m] = *(const f32x4*)(rowp + m * 16 + g * 4);
            } else {
                w[t][m] = f32x4{0.f, 0.f, 0.f, 0.f};   // pad rows only feed outputs
            }                                           // we never store
        }
    }

    // ---- convert to bf16 fragments (order = load order; permutation cancels) ----
    bf16x8 fr[2][4];
    #pragma unroll
    for (int t = 0; t < 2; ++t)
        #pragma unroll
        for (int n = 0; n < 32; ++n)
            fr[t][n >> 3][n & 7] = f2bf(w[t][n >> 2][n & 3]);

    // ---- Gram tiles: (0,0), (0,1), (1,1); accumulate over 4 K-steps ----
    f32x4 a00 = {0.f,0.f,0.f,0.f}, a01 = {0.f,0.f,0.f,0.f}, a11 = {0.f,0.f,0.f,0.f};
    #pragma unroll
    for (int s = 0; s < 4; ++s) {
        a00 = __builtin_amdgcn_mfma_f32_16x16x32_bf16(fr[0][s], fr[0][s], a00, 0, 0, 0);
        a01 = __builtin_amdgcn_mfma_f32_16x16x32_bf16(fr[0][s], fr[1][s], a01, 0, 0, 0);
        a11 = __builtin_amdgcn_mfma_f32_16x16x32_bf16(fr[1][s], fr[1][s], a11, 0, 0, 0);
    }

    // ---- scatter triu values into LDS row: pairIdx(i,j) = i*(53-i)/2 + (j-i-1) ----
    // C/D map (m89-verified): col = lane&15, row = (lane>>4)*4 + reg
    float* sr = srow[wave];
    const int row0 = g * 4;
    #pragma unroll
    for (int reg = 0; reg < 4; ++reg) {
        {   // tile (0,0): i,j in 0..15
            const int i = row0 + reg, j = lrow;
            if (i < j) sr[i * (53 - i) / 2 + (j - i - 1)] = a00[reg];
        }
        {   // tile (0,1): i in 0..15 (< j always), j in 16..31
            const int i = row0 + reg, j = 16 + lrow;
            if (j < 27) sr[i * (53 - i) / 2 + (j - i - 1)] = a01[reg];
        }
        {   // tile (1,1): i,j in 16..31
            const int i = 16 + row0 + reg, j = 16 + lrow;
            if (i < j && j < 27) sr[i * (53 - i) / 2 + (j - i - 1)] = a11[reg];
        }
    }
    // same-wave producer/consumer: compiler inserts lgkmcnt, no barrier needed

    // ---- contiguous store: 6 dword instructions, 256B fully covered each ----
    float* orow = out + (size_t)r * 351;
    #pragma unroll
    for (int i = 0; i < 6; ++i) {
        const int idx = lane + i * 64;
        if (idx < 351) orow[idx] = sr[idx];
    }
}

extern "C" void kernel_launch(void* const* d_in, const int* in_sizes, int n_in,
                              void* d_out, int out_size, void* d_ws, size_t ws_size,
                              hipStream_t stream) {
    const float* bottom = (const float*)d_in[0];   // (B, 128) fp32
    const float* emb    = (const float*)d_in[1];   // (B, 26, 128) fp32
    float* out          = (float*)d_out;           // (B, 351) fp32
    const int B = in_sizes[0] / 128;
    const int blocks = (B + 3) / 4;                // 4 rows (waves) per block
    fi_mfma_kernel<<<blocks, 256, 0, stream>>>(bottom, emb, out, B);
}